// Round 1
// baseline (1036.960 us; speedup 1.0000x reference)
//
#include <hip/hip_runtime.h>

#define NB 2048
#define NT 128

// ---------------------------------------------------------------------------
// Kernel 1: action-latent MLP  (B*T, 8) -> relu(64) -> (B*T, 16), into d_ws
// ---------------------------------------------------------------------------
__global__ __launch_bounds__(256, 4) void acl_kernel(
    const float* __restrict__ acs, const float* __restrict__ acW0,
    const float* __restrict__ acb0, const float* __restrict__ acW1,
    const float* __restrict__ acb1, float* __restrict__ aclout)
{
    __shared__ float sW0[64 * 8];
    __shared__ float sW1[16 * 64];
    __shared__ float sB0[64];
    __shared__ float sB1[16];
    const int tid = threadIdx.x;
    for (int i = tid; i < 64 * 8; i += 256) sW0[i] = acW0[i];
    for (int i = tid; i < 16 * 64; i += 256) sW1[i] = acW1[i];
    if (tid < 64) sB0[tid] = acb0[tid];
    if (tid < 16) sB1[tid] = acb1[tid];
    __syncthreads();

    const int row = blockIdx.x * 256 + tid;
    const float4 x0 = *(const float4*)&acs[row * 8];
    const float4 x1 = *(const float4*)&acs[row * 8 + 4];

    float o[16];
    #pragma unroll
    for (int m = 0; m < 16; ++m) o[m] = sB1[m];

    #pragma unroll
    for (int jc = 0; jc < 16; ++jc) {
        float hq[4];
        #pragma unroll
        for (int u = 0; u < 4; ++u) {
            const int j = jc * 4 + u;
            const float4 wa = *(const float4*)&sW0[j * 8];
            const float4 wb = *(const float4*)&sW0[j * 8 + 4];
            float hv = sB0[j];
            hv = fmaf(x0.x, wa.x, hv); hv = fmaf(x0.y, wa.y, hv);
            hv = fmaf(x0.z, wa.z, hv); hv = fmaf(x0.w, wa.w, hv);
            hv = fmaf(x1.x, wb.x, hv); hv = fmaf(x1.y, wb.y, hv);
            hv = fmaf(x1.z, wb.z, hv); hv = fmaf(x1.w, wb.w, hv);
            hq[u] = fmaxf(hv, 0.f);
        }
        #pragma unroll
        for (int m = 0; m < 16; ++m) {
            const float4 wv = *(const float4*)&sW1[m * 64 + jc * 4];
            o[m] = fmaf(hq[0], wv.x, o[m]);
            o[m] = fmaf(hq[1], wv.y, o[m]);
            o[m] = fmaf(hq[2], wv.z, o[m]);
            o[m] = fmaf(hq[3], wv.w, o[m]);
        }
    }
    float4* op = (float4*)&aclout[row * 16];
    op[0] = make_float4(o[0],  o[1],  o[2],  o[3]);
    op[1] = make_float4(o[4],  o[5],  o[6],  o[7]);
    op[2] = make_float4(o[8],  o[9],  o[10], o[11]);
    op[3] = make_float4(o[12], o[13], o[14], o[15]);
}

// ---------------------------------------------------------------------------
// Kernel 2: encoder + Dopri5 time loop + decoder, one wave per batch element.
// dyn weights live in VGPRs (48 + 32 per lane); enc/dec weights transposed in
// LDS (lane-striped reads are 2-way bank-aliased = free). No __syncthreads in
// the hot loop: xbuf/hbuf are wave-private, ordering via wave_barrier +
// in-order DS pipe.
// ---------------------------------------------------------------------------
__global__ __launch_bounds__(256, 2) void ode_kernel(
    const float* __restrict__ encW0, const float* __restrict__ encb0,
    const float* __restrict__ encW1, const float* __restrict__ encb1,
    const float* __restrict__ dynW0, const float* __restrict__ dynb0,
    const float* __restrict__ dynW1, const float* __restrict__ dynb1,
    const float* __restrict__ decW0, const float* __restrict__ decb0,
    const float* __restrict__ decW1, const float* __restrict__ decb1,
    const float* __restrict__ ob,    const float* __restrict__ times,
    const float* __restrict__ aclws, float* __restrict__ out)
{
    __shared__ float sEncW0T[64 * 64];   // [k][j]
    __shared__ float sEncW1T[64 * 32];   // [j][m]
    __shared__ float sDecW0T[32 * 64];   // [k][j]
    __shared__ float sDecW1T[64 * 64];   // [j][n]
    __shared__ float sEncB0[64], sEncB1[32], sDecB0[64], sDecB1[64];
    __shared__ float xbuf[4][64];
    __shared__ float hbuf[4][64];
    __shared__ float tbuf[4][NT];

    const int tid = threadIdx.x;
    for (int i = tid; i < 64 * 64; i += 256) { int r = i >> 6, c = i & 63; sEncW0T[c * 64 + r] = encW0[i]; }
    for (int i = tid; i < 32 * 64; i += 256) { int r = i >> 6, c = i & 63; sEncW1T[c * 32 + r] = encW1[i]; }
    for (int i = tid; i < 64 * 32; i += 256) { int r = i >> 5, c = i & 31; sDecW0T[c * 64 + r] = decW0[i]; }
    for (int i = tid; i < 64 * 64; i += 256) { int r = i >> 6, c = i & 63; sDecW1T[c * 64 + r] = decW1[i]; }
    if (tid < 64) { sEncB0[tid] = encb0[tid]; sDecB0[tid] = decb0[tid]; sDecB1[tid] = decb1[tid]; }
    if (tid < 32) { sEncB1[tid] = encb1[tid]; }

    const int w    = tid >> 6;
    const int lane = tid & 63;
    const int b    = blockIdx.x * 4 + w;
    const int m    = lane & 31;
    const int jh   = (lane >> 5) * 32;   // which half of j-space this lane reduces

    // dyn weights -> registers: lane j holds dynW0 row j; lane holds half a
    // dynW1 row (output m = lane&31, j in [jh, jh+32)).
    float w0r[48];
    #pragma unroll
    for (int q = 0; q < 12; ++q) *(float4*)&w0r[q * 4] = *(const float4*)&dynW0[lane * 48 + q * 4];
    float w1r[32];
    #pragma unroll
    for (int q = 0; q < 8; ++q)  *(float4*)&w1r[q * 4] = *(const float4*)&dynW1[m * 64 + jh + q * 4];
    const float b0r = dynb0[lane];
    const float b1r = dynb1[m];

    tbuf[w][lane]      = times[b * NT + lane];
    tbuf[w][64 + lane] = times[b * NT + 64 + lane];

    __syncthreads();

    const float decB0r = sDecB0[lane];
    const float decB1r = sDecB1[lane];

    // f(x) with xbuf[w][0..47] = [y(32) | acl(16)] already written
    auto feval = [&]() -> float {
        __builtin_amdgcn_wave_barrier();
        float4 xv[12];
        #pragma unroll
        for (int q = 0; q < 12; ++q) xv[q] = *(const float4*)&xbuf[w][q * 4];
        float a0 = b0r, a1 = 0.f, a2 = 0.f, a3 = 0.f;
        #pragma unroll
        for (int q = 0; q < 12; ++q) {
            a0 = fmaf(xv[q].x, w0r[q * 4 + 0], a0);
            a1 = fmaf(xv[q].y, w0r[q * 4 + 1], a1);
            a2 = fmaf(xv[q].z, w0r[q * 4 + 2], a2);
            a3 = fmaf(xv[q].w, w0r[q * 4 + 3], a3);
        }
        const float hj = fmaxf((a0 + a1) + (a2 + a3), 0.f);
        hbuf[w][lane] = hj;
        __builtin_amdgcn_wave_barrier();
        float4 hv[8];
        #pragma unroll
        for (int q = 0; q < 8; ++q) hv[q] = *(const float4*)&hbuf[w][jh + q * 4];
        float c0 = 0.f, c1 = 0.f, c2 = 0.f, c3 = 0.f;
        #pragma unroll
        for (int q = 0; q < 8; ++q) {
            c0 = fmaf(hv[q].x, w1r[q * 4 + 0], c0);
            c1 = fmaf(hv[q].y, w1r[q * 4 + 1], c1);
            c2 = fmaf(hv[q].z, w1r[q * 4 + 2], c2);
            c3 = fmaf(hv[q].w, w1r[q * 4 + 3], c3);
        }
        float part = (c0 + c1) + (c2 + c3);
        part += __shfl_xor(part, 32, 64);   // both halves now hold o_m
        return part + b1r;
    };

    auto decode_store = [&](float yv, int t) {
        if (lane < 32) xbuf[w][lane] = yv;
        __builtin_amdgcn_wave_barrier();
        float4 xv[8];
        #pragma unroll
        for (int q = 0; q < 8; ++q) xv[q] = *(const float4*)&xbuf[w][q * 4];
        float a0 = decB0r, a1 = 0.f, a2 = 0.f, a3 = 0.f;
        #pragma unroll
        for (int q = 0; q < 8; ++q) {
            a0 = fmaf(xv[q].x, sDecW0T[(q * 4 + 0) * 64 + lane], a0);
            a1 = fmaf(xv[q].y, sDecW0T[(q * 4 + 1) * 64 + lane], a1);
            a2 = fmaf(xv[q].z, sDecW0T[(q * 4 + 2) * 64 + lane], a2);
            a3 = fmaf(xv[q].w, sDecW0T[(q * 4 + 3) * 64 + lane], a3);
        }
        const float hj = fmaxf((a0 + a1) + (a2 + a3), 0.f);
        hbuf[w][lane] = hj;
        __builtin_amdgcn_wave_barrier();
        float o0 = decB1r, o1 = 0.f, o2 = 0.f, o3 = 0.f;
        #pragma unroll
        for (int q = 0; q < 16; ++q) {
            const float4 hv = *(const float4*)&hbuf[w][q * 4];
            o0 = fmaf(hv.x, sDecW1T[(q * 4 + 0) * 64 + lane], o0);
            o1 = fmaf(hv.y, sDecW1T[(q * 4 + 1) * 64 + lane], o1);
            o2 = fmaf(hv.z, sDecW1T[(q * 4 + 2) * 64 + lane], o2);
            o3 = fmaf(hv.w, sDecW1T[(q * 4 + 3) * 64 + lane], o3);
        }
        out[(b * NT + t) * 64 + lane] = (o0 + o1) + (o2 + o3);
    };

    // ---- encoder: ob(64) -> relu(64) -> y(32), y replicated in both halves
    float y;
    {
        xbuf[w][lane] = ob[b * 64 + lane];
        __builtin_amdgcn_wave_barrier();
        float4 xv[16];
        #pragma unroll
        for (int q = 0; q < 16; ++q) xv[q] = *(const float4*)&xbuf[w][q * 4];
        float a0 = sEncB0[lane], a1 = 0.f, a2 = 0.f, a3 = 0.f;
        #pragma unroll
        for (int q = 0; q < 16; ++q) {
            a0 = fmaf(xv[q].x, sEncW0T[(q * 4 + 0) * 64 + lane], a0);
            a1 = fmaf(xv[q].y, sEncW0T[(q * 4 + 1) * 64 + lane], a1);
            a2 = fmaf(xv[q].z, sEncW0T[(q * 4 + 2) * 64 + lane], a2);
            a3 = fmaf(xv[q].w, sEncW0T[(q * 4 + 3) * 64 + lane], a3);
        }
        const float hj = fmaxf((a0 + a1) + (a2 + a3), 0.f);
        hbuf[w][lane] = hj;
        __builtin_amdgcn_wave_barrier();
        float4 hv[8];
        #pragma unroll
        for (int q = 0; q < 8; ++q) hv[q] = *(const float4*)&hbuf[w][jh + q * 4];
        float c0 = 0.f, c1 = 0.f, c2 = 0.f, c3 = 0.f;
        #pragma unroll
        for (int q = 0; q < 8; ++q) {
            c0 = fmaf(hv[q].x, sEncW1T[(jh + q * 4 + 0) * 32 + m], c0);
            c1 = fmaf(hv[q].y, sEncW1T[(jh + q * 4 + 1) * 32 + m], c1);
            c2 = fmaf(hv[q].z, sEncW1T[(jh + q * 4 + 2) * 32 + m], c2);
            c3 = fmaf(hv[q].w, sEncW1T[(jh + q * 4 + 3) * 32 + m], c3);
        }
        float part = (c0 + c1) + (c2 + c3);
        part += __shfl_xor(part, 32, 64);
        y = part + sEncB1[m];
    }

    float aclc = aclws[(b * NT + 0) * 16 + (lane & 15)];   // replicated x4
    decode_store(y, 0);

    for (int i = 0; i < NT - 1; ++i) {
        const float t0v = tbuf[w][i];
        const float t1v = tbuf[w][i + 1];
        const float hh  = (t1v - t0v) * 0.5f;                       // /K, K=2
        const float acln = aclws[(b * NT + i + 1) * 16 + (lane & 15)];
        if (lane < 16) xbuf[w][32 + lane] = aclc;

        #pragma unroll 1
        for (int sub = 0; sub < 2; ++sub) {
            const float tsub  = t0v + (float)sub * hh;
            // stage-6 time fl(tsub+hh): matches reference searchsorted('right')
            const bool  swap6 = (tsub + hh >= t1v);

            if (lane < 32) xbuf[w][lane] = y;
            const float k1 = feval();
            if (lane < 32) xbuf[w][lane] = fmaf(hh, 0.2f * k1, y);
            const float k2 = feval();
            if (lane < 32) xbuf[w][lane] = fmaf(hh, 0.075f * k1 + 0.225f * k2, y);
            const float k3 = feval();
            if (lane < 32) xbuf[w][lane] = fmaf(hh,
                (float)(44.0/45.0)*k1 + (float)(-56.0/15.0)*k2 + (float)(32.0/9.0)*k3, y);
            const float k4 = feval();
            if (lane < 32) xbuf[w][lane] = fmaf(hh,
                (float)(19372.0/6561.0)*k1 + (float)(-25360.0/2187.0)*k2
              + (float)(64448.0/6561.0)*k3 + (float)(-212.0/729.0)*k4, y);
            const float k5 = feval();
            if (swap6 && lane < 16) xbuf[w][32 + lane] = acln;   // piecewise-const switch
            if (lane < 32) xbuf[w][lane] = fmaf(hh,
                (float)(9017.0/3168.0)*k1 + (float)(-355.0/33.0)*k2
              + (float)(46732.0/5247.0)*k3 + (float)(49.0/176.0)*k4
              + (float)(-5103.0/18656.0)*k5, y);
            const float k6 = feval();
            y = fmaf(hh,
                (float)(35.0/384.0)*k1 + (float)(500.0/1113.0)*k3
              + (float)(125.0/192.0)*k4 + (float)(-2187.0/6784.0)*k5
              + (float)(11.0/84.0)*k6, y);
        }
        aclc = acln;
        decode_store(y, i + 1);
    }
}

extern "C" void kernel_launch(void* const* d_in, const int* in_sizes, int n_in,
                              void* d_out, int out_size, void* d_ws, size_t ws_size,
                              hipStream_t stream)
{
    const float* encW0 = (const float*)d_in[0];
    const float* encb0 = (const float*)d_in[1];
    const float* encW1 = (const float*)d_in[2];
    const float* encb1 = (const float*)d_in[3];
    const float* acW0  = (const float*)d_in[4];
    const float* acb0  = (const float*)d_in[5];
    const float* acW1  = (const float*)d_in[6];
    const float* acb1  = (const float*)d_in[7];
    const float* dynW0 = (const float*)d_in[8];
    const float* dynb0 = (const float*)d_in[9];
    const float* dynW1 = (const float*)d_in[10];
    const float* dynb1 = (const float*)d_in[11];
    const float* decW0 = (const float*)d_in[12];
    const float* decb0 = (const float*)d_in[13];
    const float* decW1 = (const float*)d_in[14];
    const float* decb1 = (const float*)d_in[15];
    const float* ob    = (const float*)d_in[16];
    const float* acs   = (const float*)d_in[17];
    const float* times = (const float*)d_in[18];
    float* out = (float*)d_out;
    float* acl = (float*)d_ws;   // NB*NT*16 floats = 16.8 MB scratch

    acl_kernel<<<(NB * NT) / 256, 256, 0, stream>>>(acs, acW0, acb0, acW1, acb1, acl);
    ode_kernel<<<NB / 4, 256, 0, stream>>>(encW0, encb0, encW1, encb1,
                                           dynW0, dynb0, dynW1, dynb1,
                                           decW0, decb0, decW1, decb1,
                                           ob, times, acl, out);
}

// Round 2
// 878.597 us; speedup vs baseline: 1.1802x; 1.1802x over previous
//
#include <hip/hip_runtime.h>

#define NB 2048
#define NT 128

// ---------------------------------------------------------------------------
// Kernel 1: action-latent MLP  (B*T, 8) -> relu(64) -> (B*T, 16), into d_ws
// ---------------------------------------------------------------------------
__global__ __launch_bounds__(256, 4) void acl_kernel(
    const float* __restrict__ acs, const float* __restrict__ acW0,
    const float* __restrict__ acb0, const float* __restrict__ acW1,
    const float* __restrict__ acb1, float* __restrict__ aclout)
{
    __shared__ float sW0[64 * 8];
    __shared__ float sW1[16 * 64];
    __shared__ float sB0[64];
    __shared__ float sB1[16];
    const int tid = threadIdx.x;
    for (int i = tid; i < 64 * 8; i += 256) sW0[i] = acW0[i];
    for (int i = tid; i < 16 * 64; i += 256) sW1[i] = acW1[i];
    if (tid < 64) sB0[tid] = acb0[tid];
    if (tid < 16) sB1[tid] = acb1[tid];
    __syncthreads();

    const int row = blockIdx.x * 256 + tid;
    const float4 x0 = *(const float4*)&acs[row * 8];
    const float4 x1 = *(const float4*)&acs[row * 8 + 4];

    float o[16];
    #pragma unroll
    for (int m = 0; m < 16; ++m) o[m] = sB1[m];

    #pragma unroll
    for (int jc = 0; jc < 16; ++jc) {
        float hq[4];
        #pragma unroll
        for (int u = 0; u < 4; ++u) {
            const int j = jc * 4 + u;
            const float4 wa = *(const float4*)&sW0[j * 8];
            const float4 wb = *(const float4*)&sW0[j * 8 + 4];
            float hv = sB0[j];
            hv = fmaf(x0.x, wa.x, hv); hv = fmaf(x0.y, wa.y, hv);
            hv = fmaf(x0.z, wa.z, hv); hv = fmaf(x0.w, wa.w, hv);
            hv = fmaf(x1.x, wb.x, hv); hv = fmaf(x1.y, wb.y, hv);
            hv = fmaf(x1.z, wb.z, hv); hv = fmaf(x1.w, wb.w, hv);
            hq[u] = fmaxf(hv, 0.f);
        }
        #pragma unroll
        for (int m = 0; m < 16; ++m) {
            const float4 wv = *(const float4*)&sW1[m * 64 + jc * 4];
            o[m] = fmaf(hq[0], wv.x, o[m]);
            o[m] = fmaf(hq[1], wv.y, o[m]);
            o[m] = fmaf(hq[2], wv.z, o[m]);
            o[m] = fmaf(hq[3], wv.w, o[m]);
        }
    }
    float4* op = (float4*)&aclout[row * 16];
    op[0] = make_float4(o[0],  o[1],  o[2],  o[3]);
    op[1] = make_float4(o[4],  o[5],  o[6],  o[7]);
    op[2] = make_float4(o[8],  o[9],  o[10], o[11]);
    op[3] = make_float4(o[12], o[13], o[14], o[15]);
}

// ---------------------------------------------------------------------------
// Kernel 2: encoder + Dopri5 time loop + decoder, one wave per batch element.
// v2 changes vs v1:
//  - acl never goes through LDS: per-lane partial dot (w0 acl-columns · acl)
//    precomputed once per interval for current & next latent; stage-6 switch
//    is a scalar select between two floats.
//  - x-read in feval is 8 b128 (y only, 32 floats) instead of 12.
//  - LDS writes of y/x are unpredicated: both pair-lanes hold bit-identical
//    values (post shfl_xor; fp add is commutative), same addr same data.
//  - wave-uniform bases via readfirstlane for scalar loads.
// ---------------------------------------------------------------------------
__global__ __launch_bounds__(256, 2) void ode_kernel(
    const float* __restrict__ encW0, const float* __restrict__ encb0,
    const float* __restrict__ encW1, const float* __restrict__ encb1,
    const float* __restrict__ dynW0, const float* __restrict__ dynb0,
    const float* __restrict__ dynW1, const float* __restrict__ dynb1,
    const float* __restrict__ decW0, const float* __restrict__ decb0,
    const float* __restrict__ decW1, const float* __restrict__ decb1,
    const float* __restrict__ ob,    const float* __restrict__ times,
    const float* __restrict__ aclws, float* __restrict__ out)
{
    __shared__ float sEncW0T[64 * 64];   // [k][j]
    __shared__ float sEncW1T[64 * 32];   // [j][m]
    __shared__ float sDecW0T[32 * 64];   // [k][j]
    __shared__ float sDecW1T[64 * 64];   // [j][n]
    __shared__ float sEncB0[64], sEncB1[32], sDecB0[64], sDecB1[64];
    __shared__ float xbuf[4][64];
    __shared__ float hbuf[4][64];
    __shared__ float tbuf[4][NT];

    const int tid = threadIdx.x;
    for (int i = tid; i < 64 * 64; i += 256) { int r = i >> 6, c = i & 63; sEncW0T[c * 64 + r] = encW0[i]; }
    for (int i = tid; i < 32 * 64; i += 256) { int r = i >> 6, c = i & 63; sEncW1T[c * 32 + r] = encW1[i]; }
    for (int i = tid; i < 64 * 32; i += 256) { int r = i >> 5, c = i & 31; sDecW0T[c * 64 + r] = decW0[i]; }
    for (int i = tid; i < 64 * 64; i += 256) { int r = i >> 6, c = i & 63; sDecW1T[c * 64 + r] = decW1[i]; }
    if (tid < 64) { sEncB0[tid] = encb0[tid]; sDecB0[tid] = decb0[tid]; sDecB1[tid] = decb1[tid]; }
    if (tid < 32) { sEncB1[tid] = encb1[tid]; }

    const int w    = tid >> 6;
    const int lane = tid & 63;
    const int bu   = __builtin_amdgcn_readfirstlane(blockIdx.x * 4 + w);
    const int m    = lane & 31;
    const int jh   = (lane >> 5) * 32;   // which half of j-space this lane reduces

    float* __restrict__ xb = xbuf[w];
    float* __restrict__ hb = hbuf[w];

    // dyn weights -> registers: lane j holds dynW0 row j (y-cols 0..31 then
    // acl-cols 32..47); lane holds half a dynW1 row (output m, j in [jh,jh+32)).
    float w0r[48];
    #pragma unroll
    for (int q = 0; q < 12; ++q) *(float4*)&w0r[q * 4] = *(const float4*)&dynW0[lane * 48 + q * 4];
    float w1r[32];
    #pragma unroll
    for (int q = 0; q < 8; ++q)  *(float4*)&w1r[q * 4] = *(const float4*)&dynW1[m * 64 + jh + q * 4];
    const float b0r = dynb0[lane];
    const float b1r = dynb1[m];

    tbuf[w][lane]      = times[bu * NT + lane];
    tbuf[w][64 + lane] = times[bu * NT + 64 + lane];

    __syncthreads();

    const float decB0r = sDecB0[lane];
    const float decB1r = sDecB1[lane];

    // f(x): xb[0..31] = y already written; hinit = b0 + acl-part of the dot
    auto feval = [&](float hinit) -> float {
        __builtin_amdgcn_wave_barrier();
        float4 xv[8];
        #pragma unroll
        for (int q = 0; q < 8; ++q) xv[q] = *(const float4*)&xb[q * 4];
        float a0 = hinit, a1 = 0.f, a2 = 0.f, a3 = 0.f;
        #pragma unroll
        for (int q = 0; q < 8; ++q) {
            a0 = fmaf(xv[q].x, w0r[q * 4 + 0], a0);
            a1 = fmaf(xv[q].y, w0r[q * 4 + 1], a1);
            a2 = fmaf(xv[q].z, w0r[q * 4 + 2], a2);
            a3 = fmaf(xv[q].w, w0r[q * 4 + 3], a3);
        }
        const float hj = fmaxf((a0 + a1) + (a2 + a3), 0.f);
        hb[lane] = hj;
        __builtin_amdgcn_wave_barrier();
        float4 hv[8];
        #pragma unroll
        for (int q = 0; q < 8; ++q) hv[q] = *(const float4*)&hb[jh + q * 4];
        float c0 = 0.f, c1 = 0.f, c2 = 0.f, c3 = 0.f;
        #pragma unroll
        for (int q = 0; q < 8; ++q) {
            c0 = fmaf(hv[q].x, w1r[q * 4 + 0], c0);
            c1 = fmaf(hv[q].y, w1r[q * 4 + 1], c1);
            c2 = fmaf(hv[q].z, w1r[q * 4 + 2], c2);
            c3 = fmaf(hv[q].w, w1r[q * 4 + 3], c3);
        }
        float part = (c0 + c1) + (c2 + c3);
        part += __shfl_xor(part, 32, 64);   // both halves now hold o_m
        return part + b1r;
    };

    auto decode_store = [&](float yv, int t) {
        xb[m] = yv;                          // both pair-lanes: same addr, same data
        __builtin_amdgcn_wave_barrier();
        float4 xv[8];
        #pragma unroll
        for (int q = 0; q < 8; ++q) xv[q] = *(const float4*)&xb[q * 4];
        float a0 = decB0r, a1 = 0.f, a2 = 0.f, a3 = 0.f;
        #pragma unroll
        for (int q = 0; q < 8; ++q) {
            a0 = fmaf(xv[q].x, sDecW0T[(q * 4 + 0) * 64 + lane], a0);
            a1 = fmaf(xv[q].y, sDecW0T[(q * 4 + 1) * 64 + lane], a1);
            a2 = fmaf(xv[q].z, sDecW0T[(q * 4 + 2) * 64 + lane], a2);
            a3 = fmaf(xv[q].w, sDecW0T[(q * 4 + 3) * 64 + lane], a3);
        }
        const float hj = fmaxf((a0 + a1) + (a2 + a3), 0.f);
        hb[lane] = hj;
        __builtin_amdgcn_wave_barrier();
        float o0 = decB1r, o1 = 0.f, o2 = 0.f, o3 = 0.f;
        #pragma unroll
        for (int q = 0; q < 16; ++q) {
            const float4 hv = *(const float4*)&hb[q * 4];
            o0 = fmaf(hv.x, sDecW1T[(q * 4 + 0) * 64 + lane], o0);
            o1 = fmaf(hv.y, sDecW1T[(q * 4 + 1) * 64 + lane], o1);
            o2 = fmaf(hv.z, sDecW1T[(q * 4 + 2) * 64 + lane], o2);
            o3 = fmaf(hv.w, sDecW1T[(q * 4 + 3) * 64 + lane], o3);
        }
        out[(bu * NT + t) * 64 + lane] = (o0 + o1) + (o2 + o3);
    };

    // ---- encoder: ob(64) -> relu(64) -> y(32), y replicated in both halves
    float y;
    {
        xb[lane] = ob[bu * 64 + lane];
        __builtin_amdgcn_wave_barrier();
        float4 xv[16];
        #pragma unroll
        for (int q = 0; q < 16; ++q) xv[q] = *(const float4*)&xb[q * 4];
        float a0 = sEncB0[lane], a1 = 0.f, a2 = 0.f, a3 = 0.f;
        #pragma unroll
        for (int q = 0; q < 16; ++q) {
            a0 = fmaf(xv[q].x, sEncW0T[(q * 4 + 0) * 64 + lane], a0);
            a1 = fmaf(xv[q].y, sEncW0T[(q * 4 + 1) * 64 + lane], a1);
            a2 = fmaf(xv[q].z, sEncW0T[(q * 4 + 2) * 64 + lane], a2);
            a3 = fmaf(xv[q].w, sEncW0T[(q * 4 + 3) * 64 + lane], a3);
        }
        const float hj = fmaxf((a0 + a1) + (a2 + a3), 0.f);
        hb[lane] = hj;
        __builtin_amdgcn_wave_barrier();
        float4 hv[8];
        #pragma unroll
        for (int q = 0; q < 8; ++q) hv[q] = *(const float4*)&hb[jh + q * 4];
        float c0 = 0.f, c1 = 0.f, c2 = 0.f, c3 = 0.f;
        #pragma unroll
        for (int q = 0; q < 8; ++q) {
            c0 = fmaf(hv[q].x, sEncW1T[(jh + q * 4 + 0) * 32 + m], c0);
            c1 = fmaf(hv[q].y, sEncW1T[(jh + q * 4 + 1) * 32 + m], c1);
            c2 = fmaf(hv[q].z, sEncW1T[(jh + q * 4 + 2) * 32 + m], c2);
            c3 = fmaf(hv[q].w, sEncW1T[(jh + q * 4 + 3) * 32 + m], c3);
        }
        float part = (c0 + c1) + (c2 + c3);
        part += __shfl_xor(part, 32, 64);
        y = part + sEncB1[m];
    }

    // per-lane acl partial: aclPart = sum_k w0[lane][32+k] * acl[k]
    auto acl_part = [&](const float* __restrict__ ap) -> float {
        float4 a0 = *(const float4*)&ap[0];
        float4 a1 = *(const float4*)&ap[4];
        float4 a2 = *(const float4*)&ap[8];
        float4 a3 = *(const float4*)&ap[12];
        float s0 = 0.f, s1 = 0.f;
        s0 = fmaf(a0.x, w0r[32], s0); s1 = fmaf(a0.y, w0r[33], s1);
        s0 = fmaf(a0.z, w0r[34], s0); s1 = fmaf(a0.w, w0r[35], s1);
        s0 = fmaf(a1.x, w0r[36], s0); s1 = fmaf(a1.y, w0r[37], s1);
        s0 = fmaf(a1.z, w0r[38], s0); s1 = fmaf(a1.w, w0r[39], s1);
        s0 = fmaf(a2.x, w0r[40], s0); s1 = fmaf(a2.y, w0r[41], s1);
        s0 = fmaf(a2.z, w0r[42], s0); s1 = fmaf(a2.w, w0r[43], s1);
        s0 = fmaf(a3.x, w0r[44], s0); s1 = fmaf(a3.y, w0r[45], s1);
        s0 = fmaf(a3.z, w0r[46], s0); s1 = fmaf(a3.w, w0r[47], s1);
        return s0 + s1;
    };

    float aclPartC = acl_part(aclws + (size_t)(bu * NT) * 16);
    decode_store(y, 0);

    for (int i = 0; i < NT - 1; ++i) {
        const float t0v = tbuf[w][i];
        const float t1v = tbuf[w][i + 1];
        const float hh  = (t1v - t0v) * 0.5f;                       // /K, K=2
        const float aclPartN = acl_part(aclws + (size_t)(bu * NT + i + 1) * 16);

        #pragma unroll 1
        for (int sub = 0; sub < 2; ++sub) {
            const float tsub  = t0v + (float)sub * hh;
            // stage-6 time fl(tsub+hh): matches reference searchsorted('right')
            const bool  swap6 = (tsub + hh >= t1v);
            const float hpC = b0r + aclPartC;
            const float hp6 = b0r + (swap6 ? aclPartN : aclPartC);

            xb[m] = y;
            const float k1 = feval(hpC);
            xb[m] = fmaf(hh, 0.2f * k1, y);
            const float k2 = feval(hpC);
            xb[m] = fmaf(hh, 0.075f * k1 + 0.225f * k2, y);
            const float k3 = feval(hpC);
            xb[m] = fmaf(hh,
                (float)(44.0/45.0)*k1 + (float)(-56.0/15.0)*k2 + (float)(32.0/9.0)*k3, y);
            const float k4 = feval(hpC);
            xb[m] = fmaf(hh,
                (float)(19372.0/6561.0)*k1 + (float)(-25360.0/2187.0)*k2
              + (float)(64448.0/6561.0)*k3 + (float)(-212.0/729.0)*k4, y);
            const float k5 = feval(hpC);
            xb[m] = fmaf(hh,
                (float)(9017.0/3168.0)*k1 + (float)(-355.0/33.0)*k2
              + (float)(46732.0/5247.0)*k3 + (float)(49.0/176.0)*k4
              + (float)(-5103.0/18656.0)*k5, y);
            const float k6 = feval(hp6);
            y = fmaf(hh,
                (float)(35.0/384.0)*k1 + (float)(500.0/1113.0)*k3
              + (float)(125.0/192.0)*k4 + (float)(-2187.0/6784.0)*k5
              + (float)(11.0/84.0)*k6, y);
        }
        aclPartC = aclPartN;
        decode_store(y, i + 1);
    }
}

extern "C" void kernel_launch(void* const* d_in, const int* in_sizes, int n_in,
                              void* d_out, int out_size, void* d_ws, size_t ws_size,
                              hipStream_t stream)
{
    const float* encW0 = (const float*)d_in[0];
    const float* encb0 = (const float*)d_in[1];
    const float* encW1 = (const float*)d_in[2];
    const float* encb1 = (const float*)d_in[3];
    const float* acW0  = (const float*)d_in[4];
    const float* acb0  = (const float*)d_in[5];
    const float* acW1  = (const float*)d_in[6];
    const float* acb1  = (const float*)d_in[7];
    const float* dynW0 = (const float*)d_in[8];
    const float* dynb0 = (const float*)d_in[9];
    const float* dynW1 = (const float*)d_in[10];
    const float* dynb1 = (const float*)d_in[11];
    const float* decW0 = (const float*)d_in[12];
    const float* decb0 = (const float*)d_in[13];
    const float* decW1 = (const float*)d_in[14];
    const float* decb1 = (const float*)d_in[15];
    const float* ob    = (const float*)d_in[16];
    const float* acs   = (const float*)d_in[17];
    const float* times = (const float*)d_in[18];
    float* out = (float*)d_out;
    float* acl = (float*)d_ws;   // NB*NT*16 floats = 16.8 MB scratch

    acl_kernel<<<(NB * NT) / 256, 256, 0, stream>>>(acs, acW0, acb0, acW1, acb1, acl);
    ode_kernel<<<NB / 4, 256, 0, stream>>>(encW0, encb0, encW1, encb1,
                                           dynW0, dynb0, dynW1, dynb1,
                                           decW0, decb0, decW1, decb1,
                                           ob, times, acl, out);
}